// Round 1
// baseline (1676.749 us; speedup 1.0000x reference)
//
#include <hip/hip_runtime.h>
#include <hip/hip_bf16.h>
#include <cstdint>
#include <cstddef>

#define NUM_TOKENS 4096
#define HIDDEN     2048
#define INTER      4096
#define NEXPERTS   8
#define NPAIRS     (NUM_TOKENS * 2)   // 8192 (token, expert) pairs total

typedef __attribute__((ext_vector_type(8))) short bf16x8;
typedef __attribute__((ext_vector_type(4))) float f32x4;

// ---------------------------------------------------------------------------
// async global->LDS, 16B per lane. LDS dest = wave-uniform base + lane*16.
// Global source address is PER-LANE (this is what lets us gather rows).
// ---------------------------------------------------------------------------
typedef __attribute__((address_space(1))) void* as1_ptr;
typedef __attribute__((address_space(3))) void* as3_ptr;

__device__ __forceinline__ void load16_lds(const void* g, void* l) {
    __builtin_amdgcn_global_load_lds(
        (as1_ptr)(uintptr_t)g,
        (as3_ptr)(uint32_t)(uintptr_t)l,
        16, 0, 0);
}

// ---------------------------------------------------------------------------
// Router: softmax -> top2 -> normalized weights, compact slot assignment.
// Single block so shared-memory counters give a global prefix.
// ---------------------------------------------------------------------------
__global__ void router_kernel(const float* __restrict__ logits,
                              int*   __restrict__ token_of_slot,  // [NPAIRS]
                              int*   __restrict__ token_slots,    // [NUM_TOKENS][2]
                              float* __restrict__ token_wts,      // [NUM_TOKENS][2]
                              int*   __restrict__ expert_bounds)  // [2*NEXPERTS] start,end
{
    __shared__ int s_cnt[NEXPERTS];
    __shared__ int s_pos[NEXPERTS];
    __shared__ int s_off[NEXPERTS + 1];
    const int tid = threadIdx.x;
    if (tid < NEXPERTS) { s_cnt[tid] = 0; s_pos[tid] = 0; }
    __syncthreads();

    // pass 1: counts
    for (int t = tid; t < NUM_TOKENS; t += blockDim.x) {
        float l[NEXPERTS];
#pragma unroll
        for (int e = 0; e < NEXPERTS; e++) l[e] = logits[t * NEXPERTS + e];
        int i0 = 0; float v0 = l[0];
#pragma unroll
        for (int e = 1; e < NEXPERTS; e++) if (l[e] > v0) { v0 = l[e]; i0 = e; }
        int i1 = -1; float v1 = -1e30f;
#pragma unroll
        for (int e = 0; e < NEXPERTS; e++) if (e != i0 && l[e] > v1) { v1 = l[e]; i1 = e; }
        atomicAdd(&s_cnt[i0], 1);
        atomicAdd(&s_cnt[i1], 1);
    }
    __syncthreads();
    if (tid == 0) {
        int a = 0;
        for (int e = 0; e < NEXPERTS; e++) { s_off[e] = a; a += s_cnt[e]; }
        s_off[NEXPERTS] = a;  // == NPAIRS
    }
    __syncthreads();

    // pass 2: assign slots + per-token combine info
    for (int t = tid; t < NUM_TOKENS; t += blockDim.x) {
        float l[NEXPERTS];
#pragma unroll
        for (int e = 0; e < NEXPERTS; e++) l[e] = logits[t * NEXPERTS + e];
        int i0 = 0; float v0 = l[0];
#pragma unroll
        for (int e = 1; e < NEXPERTS; e++) if (l[e] > v0) { v0 = l[e]; i0 = e; }
        int i1 = -1; float v1 = -1e30f;
#pragma unroll
        for (int e = 0; e < NEXPERTS; e++) if (e != i0 && l[e] > v1) { v1 = l[e]; i1 = e; }
        // normalized top-2 weights: p0/(p0+p1) = 1/(1+exp(l1-l0))
        const float w0 = 1.f / (1.f + expf(v1 - v0));
        const float w1 = 1.f - w0;
        const int slot0 = s_off[i0] + atomicAdd(&s_pos[i0], 1);
        const int slot1 = s_off[i1] + atomicAdd(&s_pos[i1], 1);
        token_of_slot[slot0] = t;
        token_of_slot[slot1] = t;
        token_slots[2 * t + 0] = slot0;
        token_slots[2 * t + 1] = slot1;
        token_wts[2 * t + 0] = w0;
        token_wts[2 * t + 1] = w1;
    }
    __syncthreads();
    if (tid < NEXPERTS) {
        expert_bounds[tid] = s_off[tid];
        expert_bounds[NEXPERTS + tid] = s_off[tid + 1];
    }
}

// ---------------------------------------------------------------------------
// x f32 -> bf16  (4 elems/thread, exact grid)
// ---------------------------------------------------------------------------
__global__ void cast_x_kernel(const float* __restrict__ x,
                              __hip_bfloat16* __restrict__ xb)
{
    const size_t i = ((size_t)blockIdx.x * 256 + threadIdx.x) * 4;
    const float4 v = *(const float4*)(x + i);
    union { __hip_bfloat162 h[2]; uint64_t u; } p;
    p.h[0] = __float22bfloat162_rn(make_float2(v.x, v.y));
    p.h[1] = __float22bfloat162_rn(make_float2(v.z, v.w));
    *(uint64_t*)(xb + i) = p.u;
}

// ---------------------------------------------------------------------------
// GEMM1 (grouped, gathered): for each expert e, rows = gathered x tokens.
//   up[m][j]   = sum_k x[m][k] * w31[e][j][k]           (j in [0,INTER))
//   gate[m][j] = sum_k x[m][k] * w31[e][INTER+j][k]
//   inter[slot][j] = silu(gate) * up                     (bf16)
// Block: 128 rows x 64 inter-cols (stages 64 up-rows + 64 gate-rows of W).
// 4 waves, each computes 32 rows x 128 LDS-B-cols -> owns up&gate pairs.
// ---------------------------------------------------------------------------
__global__ __launch_bounds__(256) void gemm1_kernel(
    const __hip_bfloat16* __restrict__ xb,       // [NUM_TOKENS][HIDDEN]
    const float* __restrict__ w31,               // [E][2*INTER][HIDDEN]
    __hip_bfloat16* __restrict__ inter,          // [NPAIRS][INTER]
    const int* __restrict__ token_of_slot,
    const int* __restrict__ expert_bounds)
{
    const int e     = blockIdx.z;
    const int start = expert_bounds[e];
    const int end   = expert_bounds[NEXPERTS + e];
    const int mbase = start + blockIdx.y * 128;
    if (mbase >= end) return;
    const int nt = blockIdx.x;   // 64 tiles of 64 inter-cols

    __shared__ __hip_bfloat16 sA[128 * 32];
    __shared__ __hip_bfloat16 sB[128 * 32];   // rows 0..63 = up, 64..127 = gate

    const int tid  = threadIdx.x;
    const int wid  = tid >> 6;
    const int lane = tid & 63;
    const int lr   = lane & 15;   // MFMA side index
    const int lk   = lane >> 4;   // MFMA k-chunk

    // --- A staging (gather): wave wid, issue i covers LDS rows (wid*2+i)*16
    const __hip_bfloat16* aptr[2];
#pragma unroll
    for (int i = 0; i < 2; i++) {
        const int r = (wid * 2 + i) * 16 + (lane >> 2);
        int slot = mbase + r;
        slot = slot > NPAIRS - 1 ? NPAIRS - 1 : slot;
        const int tok = token_of_slot[slot];
        aptr[i] = xb + (size_t)tok * HIDDEN + (lane & 3) * 8;
    }

    // --- B staging: thread -> row tid/2 (0..127), k-half tid&1
    const int brow = tid >> 1, bh = tid & 1;
    const int wrow = (brow < 64) ? (nt * 64 + brow)
                                 : (INTER + nt * 64 + (brow - 64));
    const float* bptr = w31 + ((size_t)e * 2 * INTER + wrow) * HIDDEN + bh * 16;
    __hip_bfloat162* sBw = (__hip_bfloat162*)&sB[brow * 32 + bh * 16];

    f32x4 acc[2][8];
#pragma unroll
    for (int m = 0; m < 2; m++)
#pragma unroll
        for (int n = 0; n < 8; n++) acc[m][n] = (f32x4){0.f, 0.f, 0.f, 0.f};

    const __hip_bfloat16* lA = &sA[(wid * 32 + lr) * 32 + lk * 8];
    const __hip_bfloat16* lB = &sB[lr * 32 + lk * 8];

    for (int k0 = 0; k0 < HIDDEN; k0 += 32) {
        load16_lds(aptr[0] + k0, &sA[(wid * 2 + 0) * 512]);
        load16_lds(aptr[1] + k0, &sA[(wid * 2 + 1) * 512]);

        const float4 f0 = *(const float4*)(bptr + k0);
        const float4 f1 = *(const float4*)(bptr + k0 + 4);
        const float4 f2 = *(const float4*)(bptr + k0 + 8);
        const float4 f3 = *(const float4*)(bptr + k0 + 12);
        sBw[0] = __float22bfloat162_rn(make_float2(f0.x, f0.y));
        sBw[1] = __float22bfloat162_rn(make_float2(f0.z, f0.w));
        sBw[2] = __float22bfloat162_rn(make_float2(f1.x, f1.y));
        sBw[3] = __float22bfloat162_rn(make_float2(f1.z, f1.w));
        sBw[4] = __float22bfloat162_rn(make_float2(f2.x, f2.y));
        sBw[5] = __float22bfloat162_rn(make_float2(f2.z, f2.w));
        sBw[6] = __float22bfloat162_rn(make_float2(f3.x, f3.y));
        sBw[7] = __float22bfloat162_rn(make_float2(f3.z, f3.w));

        __syncthreads();   // drains vmcnt (incl. global_load_lds) + lgkmcnt

        const bf16x8 a0 = *(const bf16x8*)lA;
        const bf16x8 a1 = *(const bf16x8*)(lA + 16 * 32);
#pragma unroll
        for (int n = 0; n < 8; n++) {
            const bf16x8 b = *(const bf16x8*)(lB + n * 16 * 32);
            acc[0][n] = __builtin_amdgcn_mfma_f32_16x16x32_bf16(a0, b, acc[0][n], 0, 0, 0);
            acc[1][n] = __builtin_amdgcn_mfma_f32_16x16x32_bf16(a1, b, acc[1][n], 0, 0, 0);
        }
        __syncthreads();
    }

    // epilogue: silu(gate)*up, masked write (partial tiles at expert boundary)
#pragma unroll
    for (int m = 0; m < 2; m++) {
#pragma unroll
        for (int n = 0; n < 4; n++) {
#pragma unroll
            for (int r = 0; r < 4; r++) {
                const int row  = wid * 32 + m * 16 + lk * 4 + r;
                const int slot = mbase + row;
                if (slot < end) {
                    const float u = acc[m][n][r];
                    const float g = acc[m][n + 4][r];
                    const float s = g / (1.f + __expf(-g));
                    const int col = nt * 64 + n * 16 + lr;
                    inter[(size_t)slot * INTER + col] = __float2bfloat16(s * u);
                }
            }
        }
    }
}

// ---------------------------------------------------------------------------
// GEMM2 (grouped, contiguous rows): y[slot][n] = sum_k inter[slot][k]*w2[e][n][k]
// Block: 128 rows x 128 cols; wave tile 32x128; writes f32 y_buf.
// ---------------------------------------------------------------------------
__global__ __launch_bounds__(256) void gemm2_kernel(
    const __hip_bfloat16* __restrict__ inter,    // [NPAIRS][INTER]
    const float* __restrict__ w2,                // [E][HIDDEN][INTER]
    float* __restrict__ ybuf,                    // [NPAIRS][HIDDEN]
    const int* __restrict__ expert_bounds)
{
    const int e     = blockIdx.z;
    const int start = expert_bounds[e];
    const int end   = expert_bounds[NEXPERTS + e];
    const int mbase = start + blockIdx.y * 128;
    if (mbase >= end) return;
    const int nt = blockIdx.x;   // 16 tiles of 128 cols

    __shared__ __hip_bfloat16 sA[128 * 32];
    __shared__ __hip_bfloat16 sB[128 * 32];

    const int tid  = threadIdx.x;
    const int wid  = tid >> 6;
    const int lane = tid & 63;
    const int lr   = lane & 15;
    const int lk   = lane >> 4;

    const __hip_bfloat16* aptr[2];
#pragma unroll
    for (int i = 0; i < 2; i++) {
        const int r = (wid * 2 + i) * 16 + (lane >> 2);
        int slot = mbase + r;
        slot = slot > NPAIRS - 1 ? NPAIRS - 1 : slot;
        aptr[i] = inter + (size_t)slot * INTER + (lane & 3) * 8;
    }

    const int brow = tid >> 1, bh = tid & 1;
    const int grow = nt * 128 + brow;
    const float* bptr = w2 + ((size_t)e * HIDDEN + grow) * INTER + bh * 16;
    __hip_bfloat162* sBw = (__hip_bfloat162*)&sB[brow * 32 + bh * 16];

    f32x4 acc[2][8];
#pragma unroll
    for (int m = 0; m < 2; m++)
#pragma unroll
        for (int n = 0; n < 8; n++) acc[m][n] = (f32x4){0.f, 0.f, 0.f, 0.f};

    const __hip_bfloat16* lA = &sA[(wid * 32 + lr) * 32 + lk * 8];
    const __hip_bfloat16* lB = &sB[lr * 32 + lk * 8];

    for (int k0 = 0; k0 < INTER; k0 += 32) {
        load16_lds(aptr[0] + k0, &sA[(wid * 2 + 0) * 512]);
        load16_lds(aptr[1] + k0, &sA[(wid * 2 + 1) * 512]);

        const float4 f0 = *(const float4*)(bptr + k0);
        const float4 f1 = *(const float4*)(bptr + k0 + 4);
        const float4 f2 = *(const float4*)(bptr + k0 + 8);
        const float4 f3 = *(const float4*)(bptr + k0 + 12);
        sBw[0] = __float22bfloat162_rn(make_float2(f0.x, f0.y));
        sBw[1] = __float22bfloat162_rn(make_float2(f0.z, f0.w));
        sBw[2] = __float22bfloat162_rn(make_float2(f1.x, f1.y));
        sBw[3] = __float22bfloat162_rn(make_float2(f1.z, f1.w));
        sBw[4] = __float22bfloat162_rn(make_float2(f2.x, f2.y));
        sBw[5] = __float22bfloat162_rn(make_float2(f2.z, f2.w));
        sBw[6] = __float22bfloat162_rn(make_float2(f3.x, f3.y));
        sBw[7] = __float22bfloat162_rn(make_float2(f3.z, f3.w));

        __syncthreads();

        const bf16x8 a0 = *(const bf16x8*)lA;
        const bf16x8 a1 = *(const bf16x8*)(lA + 16 * 32);
#pragma unroll
        for (int n = 0; n < 8; n++) {
            const bf16x8 b = *(const bf16x8*)(lB + n * 16 * 32);
            acc[0][n] = __builtin_amdgcn_mfma_f32_16x16x32_bf16(a0, b, acc[0][n], 0, 0, 0);
            acc[1][n] = __builtin_amdgcn_mfma_f32_16x16x32_bf16(a1, b, acc[1][n], 0, 0, 0);
        }
        __syncthreads();
    }

#pragma unroll
    for (int m = 0; m < 2; m++) {
#pragma unroll
        for (int n = 0; n < 8; n++) {
#pragma unroll
            for (int r = 0; r < 4; r++) {
                const int row  = wid * 32 + m * 16 + lk * 4 + r;
                const int slot = mbase + row;
                if (slot < end) {
                    const int col = nt * 128 + n * 16 + lr;
                    ybuf[(size_t)slot * HIDDEN + col] = acc[m][n][r];
                }
            }
        }
    }
}

// ---------------------------------------------------------------------------
// Combine: out[t] = w0*y[slot0] + w1*y[slot1]   (fully writes d_out)
// ---------------------------------------------------------------------------
__global__ void combine_kernel(const float* __restrict__ ybuf,
                               const int*   __restrict__ token_slots,
                               const float* __restrict__ token_wts,
                               float* __restrict__ out)
{
    const int t  = blockIdx.x;
    const int s0 = token_slots[2 * t + 0];
    const int s1 = token_slots[2 * t + 1];
    const float w0 = token_wts[2 * t + 0];
    const float w1 = token_wts[2 * t + 1];
    for (int c = threadIdx.x * 4; c < HIDDEN; c += blockDim.x * 4) {
        const float4 a = *(const float4*)(ybuf + (size_t)s0 * HIDDEN + c);
        const float4 b = *(const float4*)(ybuf + (size_t)s1 * HIDDEN + c);
        float4 o;
        o.x = w0 * a.x + w1 * b.x;
        o.y = w0 * a.y + w1 * b.y;
        o.z = w0 * a.z + w1 * b.z;
        o.w = w0 * a.w + w1 * b.w;
        *(float4*)(out + (size_t)t * HIDDEN + c) = o;
    }
}

// ---------------------------------------------------------------------------
extern "C" void kernel_launch(void* const* d_in, const int* in_sizes, int n_in,
                              void* d_out, int out_size, void* d_ws, size_t ws_size,
                              hipStream_t stream)
{
    const float* x      = (const float*)d_in[0];
    const float* logits = (const float*)d_in[1];
    const float* w31    = (const float*)d_in[2];
    const float* w2     = (const float*)d_in[3];
    float* out = (float*)d_out;

    char* p = (char*)d_ws;
    __hip_bfloat16* xb    = (__hip_bfloat16*)p; p += (size_t)NUM_TOKENS * HIDDEN * 2;
    __hip_bfloat16* inter = (__hip_bfloat16*)p; p += (size_t)NPAIRS * INTER * 2;
    float* ybuf           = (float*)p;          p += (size_t)NPAIRS * HIDDEN * 4;
    int* token_of_slot    = (int*)p;            p += (size_t)NPAIRS * 4;
    int* token_slots      = (int*)p;            p += (size_t)NPAIRS * 4;
    float* token_wts      = (float*)p;          p += (size_t)NPAIRS * 4;
    int* expert_bounds    = (int*)p;            p += 2 * NEXPERTS * 4;

    router_kernel<<<1, 512, 0, stream>>>(logits, token_of_slot, token_slots,
                                         token_wts, expert_bounds);
    cast_x_kernel<<<(NUM_TOKENS * HIDDEN / 4) / 256, 256, 0, stream>>>(x, xb);
    gemm1_kernel<<<dim3(INTER / 64, NUM_TOKENS / 128, NEXPERTS), 256, 0, stream>>>(
        xb, w31, inter, token_of_slot, expert_bounds);
    gemm2_kernel<<<dim3(HIDDEN / 128, NUM_TOKENS / 128, NEXPERTS), 256, 0, stream>>>(
        inter, w2, ybuf, expert_bounds);
    combine_kernel<<<NUM_TOKENS, 256, 0, stream>>>(ybuf, token_slots, token_wts, out);
}